// Round 1
// baseline (296.332 us; speedup 1.0000x reference)
//
#include <hip/hip_runtime.h>

// DTCWT level=3 on (8,512,512,3) f32 -> (8,1024,1024,3) f32.
// afb along an axis (derived from roll(-5)+fullconv+stride2+wrap):
//   out[i] = sum_t f[t] * x[(2i+5-t) mod N]
// Tile(m,n) occupies rows [m*512,m*512+512), cols [n*512,n*512+512) of out.
// Tile-local layout: lowpass 64x64 at (0,0); level-j bands (n_j=256,128,64):
//   s0 (LH) at (0,n_j), s1 (HL) at (n_j,0), s2 (HH) at (n_j,n_j).
// Combine epilogue: (a+b)/sqrt2,(a-b)/sqrt2 between tiles (0,0)&(1,1) and
// (0,1)&(1,0) on all positions except the lowpass corner.

#define FF 0.08838834764832f
#define GG 0.01122679215254f
#define HHc 0.69587998903400f
#define AAc 0.03516384f
#define BBc 0.08832942f
#define CCc 0.23389032f
#define DDc 0.76027237f
#define EEc 0.58751830f
#define KKc 0.11430184f

// [bank: 0=Faf, 1=af][tree m][lo/hi][tap]
__device__ __constant__ float c_filt[2][2][2][10] = {
  { // Faf (first stage)
    { {0.f,-FF, FF, HHc, HHc, FF,-FF, GG, GG, 0.f},
      {0.f,-GG, GG, FF, FF,-HHc, HHc,-FF,-FF, 0.f} },
    { {GG, GG,-FF, FF, HHc, HHc, FF,-FF, 0.f, 0.f},
      {0.f, 0.f,-FF,-FF, HHc,-HHc, FF, FF, GG,-GG} }
  },
  { // af (q-shift, levels >= 1)
    { {AAc, 0.f,-BBc, CCc, DDc, EEc, 0.f,-KKc, 0.f, 0.f},
      {0.f, 0.f,-KKc, 0.f, EEc,-DDc, CCc, BBc, 0.f,-AAc} },
    { {0.f, 0.f,-KKc, 0.f, EEc, DDc, CCc,-BBc, 0.f, AAc},
      {-AAc, 0.f, BBc, CCc,-DDc, EEc, 0.f,-KKc, 0.f, 0.f} }
  }
};

// Row pass (filter along H). src: [z][B][N][WC] (z stride srcPairStride),
// dst images: lo at (2z)*dstImgStride, hi at (2z+1)*dstImgStride, each B x N/2 x WC.
template<int BANK>
__global__ __launch_bounds__(256) void row_pass(
    const float* __restrict__ src, size_t srcPairStride,
    float* __restrict__ dst, size_t dstImgStride,
    int mFixed, int mFromZ, float scale,
    int N, int WC, int halfShift)
{
  const int z = blockIdx.z;
  const int m = mFromZ ? (z >> 1) : mFixed;
  const float* flo = c_filt[BANK][m][0];
  const float* fhi = c_filt[BANK][m][1];
  const int wc = blockIdx.x * blockDim.x + threadIdx.x;
  if (wc >= WC) return;
  const int half = N >> 1;
  const int i = blockIdx.y & (half - 1);
  const int b = blockIdx.y >> halfShift;
  const float* s = src + (size_t)z * srcPairStride + ((size_t)b * N) * WC + wc;
  float lo = 0.f, hi = 0.f;
#pragma unroll
  for (int t = 0; t < 10; ++t) {
    const int rr = (2 * i + 5 - t + N) & (N - 1);
    const float v = s[(size_t)rr * WC];
    lo += flo[t] * v;
    hi += fhi[t] * v;
  }
  const size_t o = ((size_t)b * half + i) * WC + wc;
  dst[(size_t)(2 * z) * dstImgStride + o] = lo * scale;
  dst[(size_t)(2 * z + 1) * dstImgStride + o] = hi * scale;
}

// Col pass (filter along W). src images: lo at (2z)*srcImgStride, hi at (2z+1)*...
// each B x H x N x 3. Writes LL (to buffer or to out lowpass corner) and the
// 3 detail bands directly into their final positions in out.
template<int BANK>
__global__ __launch_bounds__(256) void col_pass(
    const float* __restrict__ src, size_t srcImgStride,
    float* __restrict__ ll, size_t llPairStride, int llToOut,
    float* __restrict__ out,
    int nFixed, int nFromZ, int mFixed,
    int H, int N, int hShift)
{
  const int z = blockIdx.z;
  const int n = nFromZ ? (z & 1) : nFixed;
  const int m = nFromZ ? (z >> 1) : mFixed;
  const float* flo = c_filt[BANK][n][0];
  const float* fhi = c_filt[BANK][n][1];
  const int half = N >> 1;
  const int jc = blockIdx.x * blockDim.x + threadIdx.x;
  if (jc >= half * 3) return;
  const int j = jc / 3, c = jc % 3;
  const int h = blockIdx.y & (H - 1);
  const int b = blockIdx.y >> hShift;
  const size_t rowOff = ((size_t)b * H + h) * (size_t)(N * 3);
  const float* sLo = src + (size_t)(2 * z) * srcImgStride + rowOff;
  const float* sHi = src + (size_t)(2 * z + 1) * srcImgStride + rowOff;
  float vll = 0.f, vlh = 0.f, vhl = 0.f, vhh = 0.f;
#pragma unroll
  for (int t = 0; t < 10; ++t) {
    const int cc = (2 * j + 5 - t + N) & (N - 1);
    const float a = sLo[cc * 3 + c];
    const float d = sHi[cc * 3 + c];
    vll += flo[t] * a; vlh += fhi[t] * a;
    vhl += flo[t] * d; vhh += fhi[t] * d;
  }
  const size_t outB = (size_t)b * (1024u * 1024u * 3u);
  const int r0 = m * 512, c0 = n * 512;
  if (llToOut) {
    out[outB + ((size_t)(r0 + h) * 1024 + (c0 + j)) * 3 + c] = vll;
  } else {
    ll[(size_t)z * llPairStride + (((size_t)b * H + h) * half + j) * 3 + c] = vll;
  }
  out[outB + ((size_t)(r0 + h) * 1024 + (c0 + half + j)) * 3 + c] = vlh;        // s0 LH
  out[outB + ((size_t)(r0 + half + h) * 1024 + (c0 + j)) * 3 + c] = vhl;        // s1 HL
  out[outB + ((size_t)(r0 + half + h) * 1024 + (c0 + half + j)) * 3 + c] = vhh; // s2 HH
}

// Dual-tree combine, in place on out. g=0: tiles (0,0)&(1,1); g=1: (0,1)&(1,0).
// Skips the 64x64 lowpass corner (tile-local r<64 && col<64).
__global__ __launch_bounds__(256) void combine_k(float* __restrict__ out)
{
  const int jc = blockIdx.x * blockDim.x + threadIdx.x; // 0..1535 = 512*3
  const int col = jc / 3, c = jc % 3;
  const int r = blockIdx.y & 511;
  const int b = blockIdx.y >> 9;
  const int g = blockIdx.z;
  if (r < 64 && col < 64) return;
  const size_t base = (size_t)b * (1024u * 1024u * 3u);
  size_t ia, ib;
  if (g == 0) {
    ia = base + ((size_t)r * 1024 + col) * 3 + c;
    ib = base + ((size_t)(r + 512) * 1024 + (col + 512)) * 3 + c;
  } else {
    ia = base + ((size_t)r * 1024 + (col + 512)) * 3 + c;
    ib = base + ((size_t)(r + 512) * 1024 + col) * 3 + c;
  }
  const float va = out[ia], vb = out[ib];
  const float k = 0.70710678118654752440f;
  out[ia] = (va + vb) * k;
  out[ib] = (va - vb) * k;
}

extern "C" void kernel_launch(void* const* d_in, const int* in_sizes, int n_in,
                              void* d_out, int out_size, void* d_ws, size_t ws_size,
                              hipStream_t stream) {
  (void)in_sizes; (void)n_in; (void)out_size; (void)ws_size;
  const float* x = (const float*)d_in[0];
  float* out = (float*)d_out;
  // Workspace: A = 6,291,456 floats, B = 6,291,456 floats (50.3 MB total).
  float* A  = (float*)d_ws;
  float* Bf = A + 6291456;

  // ---- Level 0 (N=512 -> 256), Faf, x/2 folded into scale. Split over m. ----
  for (int m = 0; m < 2; ++m) {
    dim3 gR(6, 8 * 256, 1); // WC=1536 -> 6 blocks; y = B*half
    row_pass<0><<<gR, 256, 0, stream>>>(x, 0, A, 3145728, m, 0, 0.5f, 512, 1536, 8);
    for (int n = 0; n < 2; ++n) {
      dim3 gC(3, 8 * 256, 1); // half*3=768 -> 3 blocks; y = B*H
      col_pass<0><<<gC, 256, 0, stream>>>(A, 3145728,
          Bf + (size_t)(m * 2 + n) * 1572864, 0, 0, out, n, 0, m, 256, 512, 8);
    }
  }
  // ---- Level 1 (256 -> 128), af, batched over 4 pairs (z). ----
  {
    dim3 g(3, 8 * 128, 4); // WC=768
    row_pass<1><<<g, 256, 0, stream>>>(Bf, 1572864, A, 786432, 0, 1, 1.f, 256, 768, 7);
  }
  {
    dim3 g(2, 8 * 128, 4); // half*3=384
    col_pass<1><<<g, 256, 0, stream>>>(A, 786432, Bf, 393216, 0, out, 0, 1, 0, 128, 256, 7);
  }
  // ---- Level 2 (128 -> 64), af. Lowpass goes straight to out. ----
  {
    dim3 g(2, 8 * 64, 4); // WC=384
    row_pass<1><<<g, 256, 0, stream>>>(Bf, 393216, A, 196608, 0, 1, 1.f, 128, 384, 6);
  }
  {
    dim3 g(1, 8 * 64, 4); // half*3=192
    col_pass<1><<<g, 256, 0, stream>>>(A, 196608, nullptr, 0, 1, out, 0, 1, 0, 64, 128, 6);
  }
  // ---- Dual-tree combine epilogue (in place on out). ----
  {
    dim3 g(6, 8 * 512, 2);
    combine_k<<<g, 256, 0, stream>>>(out);
  }
}

// Round 2
// 216.963 us; speedup vs baseline: 1.3658x; 1.3658x over previous
//
#include <hip/hip_runtime.h>

// DTCWT level=3 on (8,512,512,3) f32 -> (8,1024,1024,3) f32.
// afb along an axis: out[i] = sum_t f[t] * x[(2i+5-t) mod N]
// Tile(m,n) at rows [m*512,+512), cols [n*512,+512) of out; tile-local:
// lowpass 64x64 at (0,0); level-j bands (H=256,128,64): LH (0,H), HL (H,0), HH (H,H).
// Dual-tree combine (a+b)/sqrt2,(a-b)/sqrt2 between trees (0,0)&(1,1) and (0,1)&(1,0)
// is fused into the col passes (computed in registers, written once).

#define FF 0.08838834764832f
#define GG 0.01122679215254f
#define HHc 0.69587998903400f
#define AAc 0.03516384f
#define BBc 0.08832942f
#define CCc 0.23389032f
#define DDc 0.76027237f
#define EEc 0.58751830f
#define KKc 0.11430184f

// [bank: 0=Faf, 1=af][tree m][lo/hi][tap]
__device__ __constant__ float c_filt[2][2][2][10] = {
  { // Faf (first stage)
    { {0.f,-FF, FF, HHc, HHc, FF,-FF, GG, GG, 0.f},
      {0.f,-GG, GG, FF, FF,-HHc, HHc,-FF,-FF, 0.f} },
    { {GG, GG,-FF, FF, HHc, HHc, FF,-FF, 0.f, 0.f},
      {0.f, 0.f,-FF,-FF, HHc,-HHc, FF, FF, GG,-GG} }
  },
  { // af (q-shift, levels >= 1)
    { {AAc, 0.f,-BBc, CCc, DDc, EEc, 0.f,-KKc, 0.f, 0.f},
      {0.f, 0.f,-KKc, 0.f, EEc,-DDc, CCc, BBc, 0.f,-AAc} },
    { {0.f, 0.f,-KKc, 0.f, EEc, DDc, CCc,-BBc, 0.f, AAc},
      {-AAc, 0.f, BBc, CCc,-DDc, EEc, 0.f,-KKc, 0.f, 0.f} }
  }
};

__device__ __forceinline__ void cmb(float& a, float& b) {
  const float k = 0.70710678118654752440f;
  const float s = (a + b) * k, d = (a - b) * k;
  a = s; b = d;
}

// ---- Level 0 row pass: reads x once, applies all 4 Faf filters (m=0,1 x lo/hi).
// x: [B,512,512,3] flat; dst: 4 images [lo0,hi0,lo1,hi1], each B*256*1536 floats.
__global__ __launch_bounds__(256) void row_l0(const float* __restrict__ x,
                                              float* __restrict__ dst)
{
  const int wc = blockIdx.x * 256 + threadIdx.x;   // [0,1536)
  const int i = blockIdx.y & 255;
  const int b = blockIdx.y >> 8;
  const float* s = x + (size_t)b * (512 * 1536) + wc;
  float lo0 = 0.f, hi0 = 0.f, lo1 = 0.f, hi1 = 0.f;
#pragma unroll
  for (int t = 0; t < 10; ++t) {
    const int rr = (2 * i + 5 - t) & 511;
    const float v = s[(size_t)rr * 1536];
    lo0 += c_filt[0][0][0][t] * v;
    hi0 += c_filt[0][0][1][t] * v;
    lo1 += c_filt[0][1][0][t] * v;
    hi1 += c_filt[0][1][1][t] * v;
  }
  const size_t S = 3145728;  // B*256*512*3
  const size_t o = ((size_t)b * 256 + i) * 1536 + wc;
  dst[o]         = lo0 * 0.5f;   // x/2 folded here
  dst[S + o]     = hi0 * 0.5f;
  dst[2 * S + o] = lo1 * 0.5f;
  dst[3 * S + o] = hi1 * 0.5f;
}

// ---- Level 0 col pass: reads the 4 row images, computes all 16 subbands,
// combines dual trees in registers, writes 4 LLs to ws + 12 details to out.
__global__ __launch_bounds__(256) void col_l0(const float* __restrict__ src,
                                              float* __restrict__ ll,
                                              float* __restrict__ out)
{
  const int jc = blockIdx.x * 256 + threadIdx.x;   // [0,768)
  const int j = jc / 3, c = jc % 3;
  const int h = blockIdx.y & 255;
  const int b = blockIdx.y >> 8;
  const size_t S = 3145728;
  const size_t rowOff = ((size_t)b * 256 + h) * (512 * 3);
  const float* s0 = src + rowOff;           // lo, m=0
  const float* s1 = src + S + rowOff;       // hi, m=0
  const float* s2 = src + 2 * S + rowOff;   // lo, m=1
  const float* s3 = src + 3 * S + rowOff;   // hi, m=1
  float LL[2][2] = {}, LH[2][2] = {}, HL[2][2] = {}, HH[2][2] = {};
#pragma unroll
  for (int t = 0; t < 10; ++t) {
    const int cc = ((2 * j + 5 - t) & 511) * 3 + c;
    const float a0 = s0[cc], d0 = s1[cc], a1 = s2[cc], d1 = s3[cc];
#pragma unroll
    for (int n = 0; n < 2; ++n) {
      const float fl = c_filt[0][n][0][t], fh = c_filt[0][n][1][t];
      LL[0][n] += fl * a0; LH[0][n] += fh * a0;
      HL[0][n] += fl * d0; HH[0][n] += fh * d0;
      LL[1][n] += fl * a1; LH[1][n] += fh * a1;
      HL[1][n] += fl * d1; HH[1][n] += fh * d1;
    }
  }
  cmb(LH[0][0], LH[1][1]); cmb(LH[0][1], LH[1][0]);
  cmb(HL[0][0], HL[1][1]); cmb(HL[0][1], HL[1][0]);
  cmb(HH[0][0], HH[1][1]); cmb(HH[0][1], HH[1][0]);
  const size_t outB = (size_t)b * (1024u * 1024u * 3u);
  const size_t llO = (((size_t)b * 256 + h) * 256 + j) * 3 + c;
#pragma unroll
  for (int m = 0; m < 2; ++m)
#pragma unroll
    for (int n = 0; n < 2; ++n) {
      ll[(size_t)(m * 2 + n) * 1572864 + llO] = LL[m][n];
      const int r0 = m * 512, c0 = n * 512;
      out[outB + ((size_t)(r0 + h) * 1024 + (c0 + 256 + j)) * 3 + c] = LH[m][n];
      out[outB + ((size_t)(r0 + 256 + h) * 1024 + (c0 + j)) * 3 + c] = HL[m][n];
      out[outB + ((size_t)(r0 + 256 + h) * 1024 + (c0 + 256 + j)) * 3 + c] = HH[m][n];
    }
}

// ---- Generic af row pass, batched over z = m*2+n (4 tree chains).
// src: 4 LL images (stride srcStride); dst: 8 images lo/hi at 2z/2z+1 (stride dstStride).
__global__ __launch_bounds__(256) void row_af(
    const float* __restrict__ src, size_t srcStride,
    float* __restrict__ dst, size_t dstStride,
    int N, int WC, int halfShift)
{
  const int z = blockIdx.z;
  const int m = z >> 1;
  const int wc = blockIdx.x * 256 + threadIdx.x;
  if (wc >= WC) return;
  const int half = N >> 1;
  const int i = blockIdx.y & (half - 1);
  const int b = blockIdx.y >> halfShift;
  const float* s = src + (size_t)z * srcStride + (size_t)b * N * WC + wc;
  float lo = 0.f, hi = 0.f;
#pragma unroll
  for (int t = 0; t < 10; ++t) {
    const int rr = (2 * i + 5 - t) & (N - 1);
    const float v = s[(size_t)rr * WC];
    lo += c_filt[1][m][0][t] * v;
    hi += c_filt[1][m][1][t] * v;
  }
  const size_t o = ((size_t)b * half + i) * WC + wc;
  dst[(size_t)(2 * z) * dstStride + o] = lo;
  dst[(size_t)(2 * z + 1) * dstStride + o] = hi;
}

// ---- Generic af col pass, all 4 tree chains in one thread + fused combine.
// src: 8 images (pairs per z, stride imgStride), each B x H x N x 3, H=N/2.
template<int N, int LLOUT>
__global__ __launch_bounds__(256) void col_af(
    const float* __restrict__ src, size_t imgStride,
    float* __restrict__ ll, size_t llStride,
    float* __restrict__ out)
{
  constexpr int H = N / 2;
  constexpr int HSH = (N == 256) ? 7 : 6;
  const int jc = blockIdx.x * 256 + threadIdx.x;
  if (jc >= H * 3) return;
  const int j = jc / 3, c = jc % 3;
  const int h = blockIdx.y & (H - 1);
  const int b = blockIdx.y >> HSH;
  const size_t rowOff = ((size_t)b * H + h) * (N * 3);
  const float* sl[4]; const float* sh[4];
#pragma unroll
  for (int z = 0; z < 4; ++z) {
    sl[z] = src + (size_t)(2 * z) * imgStride + rowOff;
    sh[z] = src + (size_t)(2 * z + 1) * imgStride + rowOff;
  }
  float LL[4] = {}, LH[4] = {}, HL[4] = {}, HH[4] = {};
#pragma unroll
  for (int t = 0; t < 10; ++t) {
    const int cc = ((2 * j + 5 - t) & (N - 1)) * 3 + c;
#pragma unroll
    for (int z = 0; z < 4; ++z) {
      const int n = z & 1;
      const float fl = c_filt[1][n][0][t], fh = c_filt[1][n][1][t];
      const float a = sl[z][cc], d = sh[z][cc];
      LL[z] += fl * a; LH[z] += fh * a;
      HL[z] += fl * d; HH[z] += fh * d;
    }
  }
  cmb(LH[0], LH[3]); cmb(LH[1], LH[2]);
  cmb(HL[0], HL[3]); cmb(HL[1], HL[2]);
  cmb(HH[0], HH[3]); cmb(HH[1], HH[2]);
  const size_t outB = (size_t)b * (1024u * 1024u * 3u);
#pragma unroll
  for (int z = 0; z < 4; ++z) {
    const int m = z >> 1, n = z & 1;
    const int r0 = m * 512, c0 = n * 512;
    if (LLOUT)
      out[outB + ((size_t)(r0 + h) * 1024 + (c0 + j)) * 3 + c] = LL[z];
    else
      ll[(size_t)z * llStride + (((size_t)b * H + h) * H + j) * 3 + c] = LL[z];
    out[outB + ((size_t)(r0 + h) * 1024 + (c0 + H + j)) * 3 + c] = LH[z];
    out[outB + ((size_t)(r0 + H + h) * 1024 + (c0 + j)) * 3 + c] = HL[z];
    out[outB + ((size_t)(r0 + H + h) * 1024 + (c0 + H + j)) * 3 + c] = HH[z];
  }
}

extern "C" void kernel_launch(void* const* d_in, const int* in_sizes, int n_in,
                              void* d_out, int out_size, void* d_ws, size_t ws_size,
                              hipStream_t stream) {
  (void)in_sizes; (void)n_in; (void)out_size; (void)ws_size;
  const float* x = (const float*)d_in[0];
  float* out = (float*)d_out;
  float* A  = (float*)d_ws;        // up to 12,582,912 floats (50.3 MB)
  float* Bf = A + 12582912;        // up to  6,291,456 floats (25.2 MB)

  // Level 0 (512 -> 256), Faf bank, x/2 folded.
  row_l0<<<dim3(6, 2048), 256, 0, stream>>>(x, A);
  col_l0<<<dim3(3, 2048), 256, 0, stream>>>(A, Bf, out);
  // Level 1 (256 -> 128), af bank.
  row_af<<<dim3(3, 1024, 4), 256, 0, stream>>>(Bf, 1572864, A, 786432, 256, 768, 7);
  col_af<256, 0><<<dim3(2, 1024), 256, 0, stream>>>(A, 786432, Bf, 393216, out);
  // Level 2 (128 -> 64), af bank; LL straight to out lowpass corners.
  row_af<<<dim3(2, 512, 4), 256, 0, stream>>>(Bf, 393216, A, 196608, 128, 384, 6);
  col_af<128, 1><<<dim3(1, 512), 256, 0, stream>>>(A, 196608, nullptr, 0, out);
}

// Round 3
// 167.521 us; speedup vs baseline: 1.7689x; 1.2951x over previous
//
#include <hip/hip_runtime.h>

// DTCWT level=3 on (8,512,512,3) f32 -> (8,1024,1024,3) f32.
// One fused kernel per level: stage A row-filters (along H) from global into an
// LDS tile laid out [i][w][c][filt] (filt innermost -> ds_*_b128); stage B
// col-filters (along W) from LDS, combines the dual trees in registers, and
// writes lowpass + 3 detail bands to their final positions.
// afb: out[i] = sum_t f[t] * x[(2i+5-t) mod N]
// Tile(m,n) at rows [m*512,+512), cols [n*512,+512) of out; tile-local:
// lowpass 64x64 at (0,0); level-j bands (H=256,128,64): LH (0,H), HL (H,0), HH (H,H).

#define FF 0.08838834764832f
#define GG 0.01122679215254f
#define HHc 0.69587998903400f
#define AAc 0.03516384f
#define BBc 0.08832942f
#define CCc 0.23389032f
#define DDc 0.76027237f
#define EEc 0.58751830f
#define KKc 0.11430184f

// [bank: 0=Faf, 1=af][tree m][lo/hi][tap]
__device__ __constant__ float c_filt[2][2][2][10] = {
  { // Faf (first stage)
    { {0.f,-FF, FF, HHc, HHc, FF,-FF, GG, GG, 0.f},
      {0.f,-GG, GG, FF, FF,-HHc, HHc,-FF,-FF, 0.f} },
    { {GG, GG,-FF, FF, HHc, HHc, FF,-FF, 0.f, 0.f},
      {0.f, 0.f,-FF,-FF, HHc,-HHc, FF, FF, GG,-GG} }
  },
  { // af (q-shift, levels >= 1)
    { {AAc, 0.f,-BBc, CCc, DDc, EEc, 0.f,-KKc, 0.f, 0.f},
      {0.f, 0.f,-KKc, 0.f, EEc,-DDc, CCc, BBc, 0.f,-AAc} },
    { {0.f, 0.f,-KKc, 0.f, EEc, DDc, CCc,-BBc, 0.f, AAc},
      {-AAc, 0.f, BBc, CCc,-DDc, EEc, 0.f,-KKc, 0.f, 0.f} }
  }
};

__device__ __forceinline__ void cmb(float& a, float& b) {
  const float k = 0.70710678118654752440f;
  const float s = (a + b) * k, d = (a - b) * k;
  a = s; b = d;
}

// LVL 0: src = x [8][512][512][3], NF=4 row-filters (Faf m0lo,m0hi,m1lo,m1hi),
//        x/2 folded into stage A. LL -> llout buffer.
// LVL 1: src = LL1 [4z][8][256][256][3], NF=8 (z-chains x lo/hi, af bank).
// LVL 2: same as 1 with N=128; LL -> out lowpass corners.
template<int LVL, int N, int Ho, int Wo>
__global__ __launch_bounds__(256) void fused_level(
    const float* __restrict__ src,
    float* __restrict__ llout,
    float* __restrict__ out)
{
  constexpr int half = N / 2;
  constexpr int W2 = 2 * Wo + 8;              // col halo: wl in [0, 2Wo+8)
  constexpr int NF = (LVL == 0) ? 4 : 8;
  constexpr size_t ZS = (size_t)8 * N * N * 3;          // z stride of src (LVL>=1)
  constexpr size_t ZOUT = (size_t)8 * half * half * 3;  // z stride of llout
  __shared__ float inter[Ho][W2][3][NF];

  const int jt = blockIdx.x, it = blockIdx.y, b = blockIdx.z;
  const int i0 = it * Ho, j0 = jt * Wo;
  const int tid = threadIdx.x;

  // ---- Stage A: row filter along H, global -> LDS ----
  constexpr int itemsA = Ho * W2 * 3;
  for (int item = tid; item < itemsA; item += 256) {
    const int il = item / (W2 * 3);
    const int rm = item - il * (W2 * 3);
    const int wl = rm / 3;
    const int c  = rm - wl * 3;
    const int colg = (2 * j0 - 4 + wl) & (N - 1);
    const int ig = i0 + il;
    if (LVL == 0) {
      const float* sp = src + (((size_t)b * N) * N + colg) * 3 + c;
      float a0 = 0.f, a1 = 0.f, a2 = 0.f, a3 = 0.f;
#pragma unroll
      for (int t = 0; t < 10; ++t) {
        const int row = (2 * ig + 5 - t) & (N - 1);
        const float v = sp[(size_t)row * (N * 3)];
        a0 += c_filt[0][0][0][t] * v;
        a1 += c_filt[0][0][1][t] * v;
        a2 += c_filt[0][1][0][t] * v;
        a3 += c_filt[0][1][1][t] * v;
      }
      inter[il][wl][c][0] = a0 * 0.5f;  // x/2 folded here
      inter[il][wl][c][1] = a1 * 0.5f;
      inter[il][wl][c][2] = a2 * 0.5f;
      inter[il][wl][c][3] = a3 * 0.5f;
    } else {
      float acc[8];
#pragma unroll
      for (int f = 0; f < 8; ++f) acc[f] = 0.f;
#pragma unroll
      for (int z = 0; z < 4; ++z) {
        const int m = z >> 1;
        const float* sp = src + (size_t)z * ZS + (((size_t)b * N) * N + colg) * 3 + c;
#pragma unroll
        for (int t = 0; t < 10; ++t) {
          const int row = (2 * ig + 5 - t) & (N - 1);
          const float v = sp[(size_t)row * (N * 3)];
          acc[2 * z]     += c_filt[1][m][0][t] * v;
          acc[2 * z + 1] += c_filt[1][m][1][t] * v;
        }
      }
#pragma unroll
      for (int f = 0; f < 8; ++f) inter[il][wl][c][f] = acc[f];
    }
  }
  __syncthreads();

  // ---- Stage B: col filter along W from LDS, combine, write ----
  constexpr int itemsB = Ho * Wo * 3;
  for (int item = tid; item < itemsB; item += 256) {
    const int il = item / (Wo * 3);
    const int rm = item - il * (Wo * 3);
    const int jl = rm / 3;
    const int c  = rm - jl * 3;
    float LL[4] = {}, LH[4] = {}, HL[4] = {}, HH[4] = {};
#pragma unroll
    for (int s = 0; s < 10; ++s) {
      const int wl = 2 * jl + 9 - s;  // local col of tap s (global (2j+5-s) mod N)
      if (LVL == 0) {
        const float lo0 = inter[il][wl][c][0], hi0 = inter[il][wl][c][1];
        const float lo1 = inter[il][wl][c][2], hi1 = inter[il][wl][c][3];
#pragma unroll
        for (int n = 0; n < 2; ++n) {
          const float fl = c_filt[0][n][0][s], fh = c_filt[0][n][1][s];
          LL[n]     += fl * lo0; LH[n]     += fh * lo0;
          HL[n]     += fl * hi0; HH[n]     += fh * hi0;
          LL[2 + n] += fl * lo1; LH[2 + n] += fh * lo1;
          HL[2 + n] += fl * hi1; HH[2 + n] += fh * hi1;
        }
      } else {
#pragma unroll
        for (int z = 0; z < 4; ++z) {
          const int n = z & 1;
          const float fl = c_filt[1][n][0][s], fh = c_filt[1][n][1][s];
          const float a = inter[il][wl][c][2 * z], d = inter[il][wl][c][2 * z + 1];
          LL[z] += fl * a; LH[z] += fh * a;
          HL[z] += fl * d; HH[z] += fh * d;
        }
      }
    }
    cmb(LH[0], LH[3]); cmb(LH[1], LH[2]);
    cmb(HL[0], HL[3]); cmb(HL[1], HL[2]);
    cmb(HH[0], HH[3]); cmb(HH[1], HH[2]);
    const int ig = i0 + il, jg = j0 + jl;
    const size_t outB = (size_t)b * (1024u * 1024u * 3u);
#pragma unroll
    for (int z = 0; z < 4; ++z) {
      const int m = z >> 1, n = z & 1;
      const int r0 = m * 512, c0 = n * 512;
      if (LVL == 2)
        out[outB + ((size_t)(r0 + ig) * 1024 + (c0 + jg)) * 3 + c] = LL[z];
      else
        llout[(size_t)z * ZOUT + (((size_t)b * half + ig) * half + jg) * 3 + c] = LL[z];
      out[outB + ((size_t)(r0 + ig) * 1024 + (c0 + half + jg)) * 3 + c] = LH[z];
      out[outB + ((size_t)(r0 + half + ig) * 1024 + (c0 + jg)) * 3 + c] = HL[z];
      out[outB + ((size_t)(r0 + half + ig) * 1024 + (c0 + half + jg)) * 3 + c] = HH[z];
    }
  }
}

extern "C" void kernel_launch(void* const* d_in, const int* in_sizes, int n_in,
                              void* d_out, int out_size, void* d_ws, size_t ws_size,
                              hipStream_t stream) {
  (void)in_sizes; (void)n_in; (void)out_size; (void)ws_size;
  const float* x = (const float*)d_in[0];
  float* out = (float*)d_out;
  float* LL1 = (float*)d_ws;        // 4*8*256*256*3 = 6,291,456 floats
  float* LL2 = LL1 + 6291456;       // 4*8*128*128*3 = 1,572,864 floats

  // L0: 512 -> 256. Tile 8x32. Grid: (256/32, 256/8, 8) = 2048 blocks. LDS 27.6 KB.
  fused_level<0, 512, 8, 32><<<dim3(8, 32, 8), 256, 0, stream>>>(x, LL1, out);
  // L1: 256 -> 128. Tile 8x16. Grid: (128/16, 128/8, 8) = 1024 blocks. LDS 30.7 KB.
  fused_level<1, 256, 8, 16><<<dim3(8, 16, 8), 256, 0, stream>>>(LL1, LL2, out);
  // L2: 128 -> 64. Tile 8x16. Grid: (64/16, 64/8, 8) = 256 blocks. LDS 30.7 KB.
  fused_level<2, 128, 8, 16><<<dim3(4, 8, 8), 256, 0, stream>>>(LL2, nullptr, out);
}

// Round 5
// 166.191 us; speedup vs baseline: 1.7831x; 1.0080x over previous
//
#include <hip/hip_runtime.h>

// DTCWT level=3 on (8,512,512,3) f32 -> (8,1024,1024,3) f32.
// One fused kernel per level. Stage A row-filters (along H) with float4
// (dwordx4) global loads, register-transposes, stores float4s into an
// XOR-swizzled LDS tile (injective: swz4 permutes only low 3 bits of the
// float4 index as a function of the high bits). Stage B col-filters (along W)
// via b128 LDS reads, combines the dual trees in registers, writes
// 12 B/thread contiguous stores per band.
// afb: out[i] = sum_t f[t] * x[(2i+5-t) mod N]
// Tile(m,n) at rows [m*512,+512), cols [n*512,+512) of out; tile-local:
// lowpass 64x64 at (0,0); level-j bands (H=256,128,64): LH (0,H), HL (H,0), HH (H,H).

#define FF 0.08838834764832f
#define GG 0.01122679215254f
#define HHc 0.69587998903400f
#define AAc 0.03516384f
#define BBc 0.08832942f
#define CCc 0.23389032f
#define DDc 0.76027237f
#define EEc 0.58751830f
#define KKc 0.11430184f

// [bank: 0=Faf, 1=af][tree m][lo/hi][tap]
__device__ __constant__ float c_filt[2][2][2][10] = {
  { // Faf (first stage)
    { {0.f,-FF, FF, HHc, HHc, FF,-FF, GG, GG, 0.f},
      {0.f,-GG, GG, FF, FF,-HHc, HHc,-FF,-FF, 0.f} },
    { {GG, GG,-FF, FF, HHc, HHc, FF,-FF, 0.f, 0.f},
      {0.f, 0.f,-FF,-FF, HHc,-HHc, FF, FF, GG,-GG} }
  },
  { // af (q-shift, levels >= 1)
    { {AAc, 0.f,-BBc, CCc, DDc, EEc, 0.f,-KKc, 0.f, 0.f},
      {0.f, 0.f,-KKc, 0.f, EEc,-DDc, CCc, BBc, 0.f,-AAc} },
    { {0.f, 0.f,-KKc, 0.f, EEc, DDc, CCc,-BBc, 0.f, AAc},
      {-AAc, 0.f, BBc, CCc,-DDc, EEc, 0.f,-KKc, 0.f, 0.f} }
  }
};

__device__ __forceinline__ void cmb(float& a, float& b) {
  const float k = 0.70710678118654752440f;
  const float s = (a + b) * k, d = (a - b) * k;
  a = s; b = d;
}

// Injective bank swizzle on float4 indices: permutes low 3 bits (bank group)
// as a function of bits >=3. Range-preserving within 8-aligned octets.
__device__ __forceinline__ int swz4(int f4) { return f4 ^ ((f4 >> 3) & 7); }

template<int LVL, int N, int Ho, int Wo>
__global__ __launch_bounds__(256) void fused_level(
    const float* __restrict__ src,
    float* __restrict__ llout,
    float* __restrict__ out)
{
  constexpr int half = N / 2;
  constexpr int W2 = 2 * Wo + 8;               // col halo span
  constexpr int NF = (LVL == 0) ? 4 : 8;       // row-filter outputs per position
  constexpr int ROWF = 3 * N;                  // floats per image row
  constexpr int FL = 3 * W2;                   // flat floats per LDS row
  constexpr int SIF4 = (3 * W2 * NF) / 4 + 4;  // il-stride in float4 units
  constexpr size_t ZS = (size_t)8 * N * N * 3;
  constexpr size_t ZOUT = (size_t)8 * half * half * 3;
  __shared__ __align__(16) float inter[Ho * SIF4 * 4];

  const int jt = blockIdx.x, it = blockIdx.y, b = blockIdx.z;
  const int i0 = it * Ho, j0 = jt * Wo;
  const int tid = threadIdx.x;

  int base = (2 * j0 - 4) * 3;                 // multiple of 4 floats (16B)
  if (base < 0) base += ROWF;

  // ---- Stage A: row filter along H, float4 global loads -> swizzled LDS ----
  constexpr int I4 = FL / 4;
  for (int item = tid; item < Ho * I4; item += 256) {
    const int il = item / I4;
    const int q4 = (item - il * I4) * 4;       // flat local (w*3+c), mult of 4
    int fg = base + q4;
    if (fg >= ROWF) fg -= ROWF;                // never straddles a float4
    const int ig = i0 + il;
    float acc[NF][4];
#pragma unroll
    for (int f = 0; f < NF; ++f)
#pragma unroll
      for (int k = 0; k < 4; ++k) acc[f][k] = 0.f;

    if constexpr (LVL == 0) {
      const float* sp = src + (size_t)b * N * ROWF + fg;
#pragma unroll
      for (int t = 0; t < 10; ++t) {
        const int r = (2 * ig + 5 - t) & (N - 1);
        const float4 v = *(const float4*)(sp + (size_t)r * ROWF);
#pragma unroll
        for (int f = 0; f < 4; ++f) {
          const float fc = c_filt[0][f >> 1][f & 1][t];
          acc[f][0] += fc * v.x; acc[f][1] += fc * v.y;
          acc[f][2] += fc * v.z; acc[f][3] += fc * v.w;
        }
      }
#pragma unroll
      for (int f = 0; f < 4; ++f)
#pragma unroll
        for (int k = 0; k < 4; ++k) acc[f][k] *= 0.5f;  // x/2 folded
    } else {
#pragma unroll
      for (int z = 0; z < 4; ++z) {
        const int m = z >> 1;
        const float* sp = src + (size_t)z * ZS + (size_t)b * N * ROWF + fg;
#pragma unroll
        for (int t = 0; t < 10; ++t) {
          const int r = (2 * ig + 5 - t) & (N - 1);
          const float4 v = *(const float4*)(sp + (size_t)r * ROWF);
          const float fl = c_filt[1][m][0][t], fh = c_filt[1][m][1][t];
          acc[2 * z][0] += fl * v.x; acc[2 * z][1] += fl * v.y;
          acc[2 * z][2] += fl * v.z; acc[2 * z][3] += fl * v.w;
          acc[2 * z + 1][0] += fh * v.x; acc[2 * z + 1][1] += fh * v.y;
          acc[2 * z + 1][2] += fh * v.z; acc[2 * z + 1][3] += fh * v.w;
        }
      }
    }
    // transpose-write: per flat position fq, NF filters contiguous as float4s.
    // NF=4: float4 index = fq. NF=8: float4 indices = 2*fq, 2*fq+1.
#pragma unroll
    for (int k = 0; k < 4; ++k) {
      const int fq = q4 + k;
      if constexpr (NF == 4) {
        float4 w = make_float4(acc[0][k], acc[1][k], acc[2][k], acc[3][k]);
        *(float4*)&inter[(il * SIF4 + swz4(fq)) * 4] = w;
      } else {
        float4 w0 = make_float4(acc[0][k], acc[1][k], acc[2][k], acc[3][k]);
        float4 w1 = make_float4(acc[4][k], acc[5][k], acc[6][k], acc[7][k]);
        *(float4*)&inter[(il * SIF4 + swz4(2 * fq)) * 4] = w0;
        *(float4*)&inter[(il * SIF4 + swz4(2 * fq + 1)) * 4] = w1;
      }
    }
  }
  __syncthreads();

  // ---- Stage B: col filter along W from LDS, combine, contiguous stores ----
  if (tid < Ho * Wo) {
    const int il = tid / Wo, jl = tid - (tid / Wo) * Wo;
    float LL[4][3] = {}, LH[4][3] = {}, HL[4][3] = {}, HH[4][3] = {};
#pragma unroll
    for (int s = 0; s < 10; ++s) {
      const int wl = 2 * jl + 9 - s;
#pragma unroll
      for (int c = 0; c < 3; ++c) {
        if constexpr (LVL == 0) {
          const int f4 = wl * 3 + c;
          const float4 v = *(const float4*)&inter[(il * SIF4 + swz4(f4)) * 4];
          const float a0 = v.x, d0 = v.y, a1 = v.z, d1 = v.w;
#pragma unroll
          for (int n = 0; n < 2; ++n) {
            const float fl = c_filt[0][n][0][s], fh = c_filt[0][n][1][s];
            LL[n][c] += fl * a0; LH[n][c] += fh * a0;
            HL[n][c] += fl * d0; HH[n][c] += fh * d0;
            LL[2 + n][c] += fl * a1; LH[2 + n][c] += fh * a1;
            HL[2 + n][c] += fl * d1; HH[2 + n][c] += fh * d1;
          }
        } else {
          const int f4 = (wl * 3 + c) * 2;
          const float4 v0 = *(const float4*)&inter[(il * SIF4 + swz4(f4)) * 4];
          const float4 v1 = *(const float4*)&inter[(il * SIF4 + swz4(f4 + 1)) * 4];
          const float az[4] = {v0.x, v0.z, v1.x, v1.z};
          const float dz[4] = {v0.y, v0.w, v1.y, v1.w};
#pragma unroll
          for (int z = 0; z < 4; ++z) {
            const int n = z & 1;
            const float fl = c_filt[1][n][0][s], fh = c_filt[1][n][1][s];
            LL[z][c] += fl * az[z]; LH[z][c] += fh * az[z];
            HL[z][c] += fl * dz[z]; HH[z][c] += fh * dz[z];
          }
        }
      }
    }
#pragma unroll
    for (int c = 0; c < 3; ++c) {
      cmb(LH[0][c], LH[3][c]); cmb(LH[1][c], LH[2][c]);
      cmb(HL[0][c], HL[3][c]); cmb(HL[1][c], HL[2][c]);
      cmb(HH[0][c], HH[3][c]); cmb(HH[1][c], HH[2][c]);
    }
    const int ig = i0 + il, jg = j0 + jl;
    const size_t outB = (size_t)b * (1024u * 1024u * 3u);
#pragma unroll
    for (int z = 0; z < 4; ++z) {
      const int m = z >> 1, n = z & 1;
      const int r0 = m * 512, c0 = n * 512;
      float* pLL;
      if constexpr (LVL == 2)
        pLL = out + outB + ((size_t)(r0 + ig) * 1024 + (c0 + jg)) * 3;
      else
        pLL = llout + (size_t)z * ZOUT + (((size_t)b * half + ig) * half + jg) * 3;
      pLL[0] = LL[z][0]; pLL[1] = LL[z][1]; pLL[2] = LL[z][2];
      float* pLH = out + outB + ((size_t)(r0 + ig) * 1024 + (c0 + half + jg)) * 3;
      pLH[0] = LH[z][0]; pLH[1] = LH[z][1]; pLH[2] = LH[z][2];
      float* pHL = out + outB + ((size_t)(r0 + half + ig) * 1024 + (c0 + jg)) * 3;
      pHL[0] = HL[z][0]; pHL[1] = HL[z][1]; pHL[2] = HL[z][2];
      float* pHH = out + outB + ((size_t)(r0 + half + ig) * 1024 + (c0 + half + jg)) * 3;
      pHH[0] = HH[z][0]; pHH[1] = HH[z][1]; pHH[2] = HH[z][2];
    }
  }
}

extern "C" void kernel_launch(void* const* d_in, const int* in_sizes, int n_in,
                              void* d_out, int out_size, void* d_ws, size_t ws_size,
                              hipStream_t stream) {
  (void)in_sizes; (void)n_in; (void)out_size; (void)ws_size;
  const float* x = (const float*)d_in[0];
  float* out = (float*)d_out;
  float* LL1 = (float*)d_ws;        // 4*8*256*256*3 = 6,291,456 floats
  float* LL2 = LL1 + 6291456;       // 4*8*128*128*3 = 1,572,864 floats

  // L0: 512->256. Tile 8x32, LDS 8*220*16 = 28160 B.
  fused_level<0, 512, 8, 32><<<dim3(8, 32, 8), 256, 0, stream>>>(x, LL1, out);
  // L1: 256->128. Tile 8x16, LDS 8*244*16 = 31232 B.
  fused_level<1, 256, 8, 16><<<dim3(8, 16, 8), 256, 0, stream>>>(LL1, LL2, out);
  // L2: 128->64. Tile 8x16.
  fused_level<2, 128, 8, 16><<<dim3(4, 8, 8), 256, 0, stream>>>(LL2, nullptr, out);
}